// Round 1
// baseline (464.064 us; speedup 1.0000x reference)
//
#include <hip/hip_runtime.h>
#include <cstdint>
#include <cstddef>

// ---------- types ----------
typedef __attribute__((ext_vector_type(8))) short bfrag;   // 8 bf16 (4 VGPR) MFMA A/B frag
typedef __attribute__((ext_vector_type(4))) float facc;    // 4 f32 MFMA C/D frag

static __device__ __forceinline__ short f2bf(float f) {
  union { float f; unsigned int u; } c; c.f = f;
  unsigned int r = (c.u + 0x7fffu + ((c.u >> 16) & 1u)) >> 16;   // RNE
  return (short)r;
}
static __device__ __forceinline__ float bf2f(short s) {
  union { float f; unsigned int u; } c; c.u = ((unsigned int)(unsigned short)s) << 16;
  return c.f;
}

// ---------- convert fp32 -> bf16 (row-major, vectorized) ----------
__global__ __launch_bounds__(256) void cvt_rows(const float* __restrict__ src,
                                                short* __restrict__ dst, size_t n8) {
  size_t i = (size_t)blockIdx.x * 256 + threadIdx.x;
  if (i >= n8) return;
  const facc* s4 = (const facc*)src;
  facc v0 = s4[i * 2], v1 = s4[i * 2 + 1];
  bfrag o;
  o[0] = f2bf(v0[0]); o[1] = f2bf(v0[1]); o[2] = f2bf(v0[2]); o[3] = f2bf(v0[3]);
  o[4] = f2bf(v1[0]); o[5] = f2bf(v1[1]); o[6] = f2bf(v1[2]); o[7] = f2bf(v1[3]);
  *(bfrag*)(dst + i * 8) = o;
}

// ---------- convert + transpose: dst[n*K+k] = bf16(src[k*N+n]) ----------
__global__ __launch_bounds__(256) void cvt_T(const float* __restrict__ src,
                                             short* __restrict__ dst, int N, int K) {
  __shared__ short tile[64][65];
  int n0 = blockIdx.x * 64, k0 = blockIdx.y * 64;
  int tx = threadIdx.x & 63, ty = threadIdx.x >> 6;
  #pragma unroll
  for (int i = ty; i < 64; i += 4)
    tile[i][tx] = f2bf(src[(size_t)(k0 + i) * N + n0 + tx]);   // coalesced read
  __syncthreads();
  #pragma unroll
  for (int i = ty; i < 64; i += 4)
    dst[(size_t)(n0 + i) * K + k0 + tx] = tile[tx][i];         // coalesced write
}

// ---------- gate: g[row] = sigmoid(x[row,:] . Wg + bg) in fp32 ----------
__global__ __launch_bounds__(256) void gate_kernel(const float* __restrict__ x,
                                                   const float* __restrict__ Wg,
                                                   const float* __restrict__ bg,
                                                   float* __restrict__ g) {
  int row = blockIdx.x * 4 + (threadIdx.x >> 6);
  int l = threadIdx.x & 63;
  const facc* xr = (const facc*)(x + (size_t)row * 1024);
  const facc* wr = (const facc*)Wg;
  float s = 0.f;
  #pragma unroll
  for (int i = 0; i < 4; ++i) {
    facc a = xr[l + 64 * i], w = wr[l + 64 * i];
    s += a[0] * w[0] + a[1] * w[1] + a[2] * w[2] + a[3] * w[3];
  }
  #pragma unroll
  for (int mm = 1; mm < 64; mm <<= 1) s += __shfl_xor(s, mm);
  if (l == 0) g[row] = 1.f / (1.f + __expf(-(s + bg[0])));
}

// ---------- bf16 GEMM: C[M,N] = A[M,K] @ Bt[N,K]^T ----------
// EPI 0: scatter into q/k/v bf16 buffers [b*16+h][s][64]   (N=3072)
// EPI 1: out fp32 [M,N] += bias                            (N=1024)
template <int EPI>
__global__ __launch_bounds__(256) void gemm_bt(
    const short* __restrict__ A, const short* __restrict__ Bt,
    int M, int N, int K,
    short* __restrict__ q_out, short* __restrict__ k_out, short* __restrict__ v_out,
    float* __restrict__ out, const float* __restrict__ bias) {
  __shared__ short Ab[128 * 32];
  __shared__ short Bb[128 * 32];
  const int t = threadIdx.x;
  const int l = t & 63;
  const int tile_m = blockIdx.y * 128;
  const int tile_n = blockIdx.x * 128;
  const int w = t >> 6;
  const int wm = (w >> 1) * 64, wn = (w & 1) * 64;
  const int c0 = t, c1 = t + 256;          // 16B chunk ids (row = c>>2, off = (c&3)*8)

  facc acc[4][4];
  #pragma unroll
  for (int i = 0; i < 4; ++i)
    #pragma unroll
    for (int j = 0; j < 4; ++j) acc[i][j] = (facc){0.f, 0.f, 0.f, 0.f};

  const short* Abase = A + (size_t)tile_m * K;
  const short* Bbase = Bt + (size_t)tile_n * K;

  for (int k0 = 0; k0 < K; k0 += 32) {
    bfrag a0 = *(const bfrag*)(Abase + (size_t)(c0 >> 2) * K + k0 + (c0 & 3) * 8);
    bfrag a1 = *(const bfrag*)(Abase + (size_t)(c1 >> 2) * K + k0 + (c1 & 3) * 8);
    bfrag b0 = *(const bfrag*)(Bbase + (size_t)(c0 >> 2) * K + k0 + (c0 & 3) * 8);
    bfrag b1 = *(const bfrag*)(Bbase + (size_t)(c1 >> 2) * K + k0 + (c1 & 3) * 8);
    __syncthreads();
    *(bfrag*)&Ab[c0 * 8] = a0;
    *(bfrag*)&Ab[c1 * 8] = a1;
    *(bfrag*)&Bb[c0 * 8] = b0;
    *(bfrag*)&Bb[c1 * 8] = b1;
    __syncthreads();
    bfrag af[4], bf[4];
    #pragma unroll
    for (int i = 0; i < 4; ++i)
      af[i] = *(const bfrag*)&Ab[(wm + i * 16 + (l & 15)) * 32 + ((l >> 4) << 3)];
    #pragma unroll
    for (int i = 0; i < 4; ++i)
      bf[i] = *(const bfrag*)&Bb[(wn + i * 16 + (l & 15)) * 32 + ((l >> 4) << 3)];
    #pragma unroll
    for (int mt = 0; mt < 4; ++mt)
      #pragma unroll
      for (int nt = 0; nt < 4; ++nt)
        acc[mt][nt] = __builtin_amdgcn_mfma_f32_16x16x32_bf16(af[mt], bf[nt], acc[mt][nt], 0, 0, 0);
  }

  #pragma unroll
  for (int mt = 0; mt < 4; ++mt)
    #pragma unroll
    for (int nt = 0; nt < 4; ++nt) {
      int col = tile_n + wn + nt * 16 + (l & 15);
      int row0 = tile_m + wm + mt * 16 + ((l >> 4) << 2);
      if (EPI == 0) {
        int which = col >> 10, rem = col & 1023, hh = rem >> 6, dd = rem & 63;
        short* dst = (which == 0) ? q_out : ((which == 1) ? k_out : v_out);
        #pragma unroll
        for (int r = 0; r < 4; ++r) {
          int m = row0 + r, b = m >> 12, s = m & 4095;
          dst[(((size_t)b * 16 + hh) * 4096 + s) * 64 + dd] = f2bf(acc[mt][nt][r]);
        }
      } else {
        float bv = bias[col];
        #pragma unroll
        for (int r = 0; r < 4; ++r)
          out[(size_t)(row0 + r) * N + col] = acc[mt][nt][r] + bv;
      }
    }
}

// ---------- flash attention, 4 waves x 16 queries, key tiles of 32 ----------
// MODE 0: local window attention -> lout bf16 [bh][s][64]
// MODE 1: strided global attention, fused gate combine -> comb bf16 [b*s][1024]
template <int MODE>
__global__ __launch_bounds__(256) void attn_kernel(
    const short* __restrict__ qb, const short* __restrict__ kb, const short* __restrict__ vb,
    short* __restrict__ lout, const short* __restrict__ lin,
    const float* __restrict__ gate, short* __restrict__ comb) {
  __shared__ short Kt[32 * 64];     // [key][d]
  __shared__ short Vt[64 * 32];     // [d][key]
  __shared__ short Pb[4][16 * 32];  // per-wave P [q][key]
  const int t = threadIdx.x, l = t & 63, w = t >> 6;
  const int bid = blockIdx.x;
  const int bh = bid >> 6, qblk = bid & 63;
  const int q0 = qblk * 64;
  const int b = bh >> 4, h = bh & 15;
  const int qw0 = q0 + w * 16;

  int kstart, nkt;
  if (MODE == 0) {
    int n = q0 >> 9;
    kstart = n * 512 - 256; if (kstart < 0) kstart = 0;
    int kend = n * 512 + 768; if (kend > 4096) kend = 4096;
    nkt = (kend - kstart) >> 5;           // always tile-aligned: no masking needed
  } else { kstart = 0; nkt = 4; }

  // Q fragments (row = qw0 + (l&15), k-chunk = (l>>4)*8, two 32-wide k-steps)
  const short* qrow_ptr = qb + ((size_t)bh * 4096 + qw0 + (l & 15)) * 64 + ((l >> 4) << 3);
  bfrag qf0 = *(const bfrag*)(qrow_ptr);
  bfrag qf1 = *(const bfrag*)(qrow_ptr + 32);

  float m_r[4], l_r[4];
  facc o[4];
  #pragma unroll
  for (int r = 0; r < 4; ++r) { m_r[r] = -1e30f; l_r[r] = 0.f; }
  #pragma unroll
  for (int nt = 0; nt < 4; ++nt) o[nt] = (facc){0.f, 0.f, 0.f, 0.f};

  const int sj = t >> 3;            // key row 0..31
  const int sd = (t & 7) * 8;       // dhead chunk

  for (int kt = 0; kt < nkt; ++kt) {
    int gk = (MODE == 0) ? (kstart + kt * 32 + sj) : ((kt * 32 + sj) * 32);
    const size_t rowoff = ((size_t)bh * 4096 + gk) * 64 + sd;
    bfrag kv = *(const bfrag*)(kb + rowoff);
    bfrag vv = *(const bfrag*)(vb + rowoff);
    __syncthreads();
    *(bfrag*)&Kt[sj * 64 + sd] = kv;
    #pragma unroll
    for (int jj = 0; jj < 8; ++jj) Vt[(sd + jj) * 32 + sj] = vv[jj];
    __syncthreads();

    // S = Q @ K^T  (two 16x16 key tiles, K=64 via 2 MFMAs each)
    facc s0 = (facc){0.f, 0.f, 0.f, 0.f}, s1 = (facc){0.f, 0.f, 0.f, 0.f};
    bfrag k0a = *(const bfrag*)&Kt[(l & 15) * 64 + ((l >> 4) << 3)];
    bfrag k0b = *(const bfrag*)&Kt[(l & 15) * 64 + 32 + ((l >> 4) << 3)];
    bfrag k1a = *(const bfrag*)&Kt[((l & 15) + 16) * 64 + ((l >> 4) << 3)];
    bfrag k1b = *(const bfrag*)&Kt[((l & 15) + 16) * 64 + 32 + ((l >> 4) << 3)];
    s0 = __builtin_amdgcn_mfma_f32_16x16x32_bf16(qf0, k0a, s0, 0, 0, 0);
    s0 = __builtin_amdgcn_mfma_f32_16x16x32_bf16(qf1, k0b, s0, 0, 0, 0);
    s1 = __builtin_amdgcn_mfma_f32_16x16x32_bf16(qf0, k1a, s1, 0, 0, 0);
    s1 = __builtin_amdgcn_mfma_f32_16x16x32_bf16(qf1, k1b, s1, 0, 0, 0);

    short* pw = &Pb[w][0];
    #pragma unroll
    for (int r = 0; r < 4; ++r) {
      float a0 = s0[r] * 0.125f, a1 = s1[r] * 0.125f;
      float mt2 = fmaxf(a0, a1);
      mt2 = fmaxf(mt2, __shfl_xor(mt2, 1));
      mt2 = fmaxf(mt2, __shfl_xor(mt2, 2));
      mt2 = fmaxf(mt2, __shfl_xor(mt2, 4));
      mt2 = fmaxf(mt2, __shfl_xor(mt2, 8));
      float mnew = fmaxf(m_r[r], mt2);
      const float L2E = 1.4426950408889634f;
      float p0 = exp2f((a0 - mnew) * L2E);
      float p1 = exp2f((a1 - mnew) * L2E);
      float corr = exp2f((m_r[r] - mnew) * L2E);
      m_r[r] = mnew;
      float rs = p0 + p1;
      rs += __shfl_xor(rs, 1);
      rs += __shfl_xor(rs, 2);
      rs += __shfl_xor(rs, 4);
      rs += __shfl_xor(rs, 8);
      l_r[r] = l_r[r] * corr + rs;
      #pragma unroll
      for (int nt = 0; nt < 4; ++nt) o[nt][r] *= corr;
      int qloc = ((l >> 4) << 2) + r;
      pw[qloc * 32 + (l & 15)] = f2bf(p0);
      pw[qloc * 32 + 16 + (l & 15)] = f2bf(p1);
    }
    // PV: O += P @ V   (A = P[q][key], B = V[key][d] read from Vt[d][key])
    bfrag pf = *(const bfrag*)&pw[(l & 15) * 32 + ((l >> 4) << 3)];
    #pragma unroll
    for (int nt = 0; nt < 4; ++nt) {
      bfrag vf = *(const bfrag*)&Vt[(nt * 16 + (l & 15)) * 32 + ((l >> 4) << 3)];
      o[nt] = __builtin_amdgcn_mfma_f32_16x16x32_bf16(pf, vf, o[nt], 0, 0, 0);
    }
  }

  #pragma unroll
  for (int nt = 0; nt < 4; ++nt) {
    int dd = nt * 16 + (l & 15);
    #pragma unroll
    for (int r = 0; r < 4; ++r) {
      int qq = qw0 + ((l >> 4) << 2) + r;
      float val = o[nt][r] / l_r[r];
      if (MODE == 0) {
        lout[((size_t)bh * 4096 + qq) * 64 + dd] = f2bf(val);
      } else {
        float gg = gate[b * 4096 + qq];
        float loc = bf2f(lin[((size_t)bh * 4096 + qq) * 64 + dd]);
        float res = gg * loc + (1.f - gg) * val;
        comb[((size_t)b * 4096 + qq) * 1024 + h * 64 + dd] = f2bf(res);
      }
    }
  }
}

// ---------- launch ----------
extern "C" void kernel_launch(void* const* d_in, const int* in_sizes, int n_in,
                              void* d_out, int out_size, void* d_ws, size_t ws_size,
                              hipStream_t stream) {
  const float* x    = (const float*)d_in[0];
  const float* Wqkv = (const float*)d_in[1];
  const float* Wg   = (const float*)d_in[2];
  const float* bg   = (const float*)d_in[3];
  const float* Wout = (const float*)d_in[4];
  const float* bout = (const float*)d_in[5];
  float* out = (float*)d_out;

  char* p = (char*)d_ws;
  short* xbf   = (short*)p; p += (size_t)8192 * 1024 * 2;   // also reused as comb
  short* WqkvT = (short*)p; p += (size_t)3072 * 1024 * 2;
  short* WoutT = (short*)p; p += (size_t)1024 * 1024 * 2;
  short* qb    = (short*)p; p += (size_t)32 * 4096 * 64 * 2;
  short* kb    = (short*)p; p += (size_t)32 * 4096 * 64 * 2;
  short* vb    = (short*)p; p += (size_t)32 * 4096 * 64 * 2;
  short* locb  = (short*)p; p += (size_t)32 * 4096 * 64 * 2;
  float* g     = (float*)p; p += (size_t)8192 * 4;
  short* comb  = xbf;  // alias: xbf dead after gemm<0>

  cvt_rows<<<4096, 256, 0, stream>>>(x, xbf, (size_t)8192 * 1024 / 8);
  cvt_T<<<dim3(48, 16), 256, 0, stream>>>(Wqkv, WqkvT, 3072, 1024);
  cvt_T<<<dim3(16, 16), 256, 0, stream>>>(Wout, WoutT, 1024, 1024);
  gate_kernel<<<2048, 256, 0, stream>>>(x, Wg, bg, g);
  gemm_bt<0><<<dim3(24, 64), 256, 0, stream>>>(xbf, WqkvT, 8192, 3072, 1024,
                                               qb, kb, vb, nullptr, nullptr);
  attn_kernel<0><<<2048, 256, 0, stream>>>(qb, kb, vb, locb, nullptr, nullptr, nullptr);
  attn_kernel<1><<<2048, 256, 0, stream>>>(qb, kb, vb, nullptr, locb, g, comb);
  gemm_bt<1><<<dim3(8, 64), 256, 0, stream>>>(comb, WoutT, 8192, 1024, 1024,
                                              nullptr, nullptr, nullptr, out, bout);
}

// Round 2
// 377.490 us; speedup vs baseline: 1.2293x; 1.2293x over previous
//
#include <hip/hip_runtime.h>
#include <cstdint>
#include <cstddef>

// ---------- types ----------
typedef __attribute__((ext_vector_type(8))) short bfrag;   // 8 bf16 (4 VGPR) MFMA A/B frag
typedef __attribute__((ext_vector_type(4))) short short4v; // 8B packed bf16 quad
typedef __attribute__((ext_vector_type(4))) float facc;    // 4 f32 MFMA C/D frag

static __device__ __forceinline__ short f2bf(float f) {
  union { float f; unsigned int u; } c; c.f = f;
  unsigned int r = (c.u + 0x7fffu + ((c.u >> 16) & 1u)) >> 16;   // RNE
  return (short)r;
}
static __device__ __forceinline__ float bf2f(short s) {
  union { float f; unsigned int u; } c; c.u = ((unsigned int)(unsigned short)s) << 16;
  return c.f;
}

// ---------- convert fp32 -> bf16 (row-major, vectorized) ----------
__global__ __launch_bounds__(256) void cvt_rows(const float* __restrict__ src,
                                                short* __restrict__ dst, size_t n8) {
  size_t i = (size_t)blockIdx.x * 256 + threadIdx.x;
  if (i >= n8) return;
  const facc* s4 = (const facc*)src;
  facc v0 = s4[i * 2], v1 = s4[i * 2 + 1];
  bfrag o;
  o[0] = f2bf(v0[0]); o[1] = f2bf(v0[1]); o[2] = f2bf(v0[2]); o[3] = f2bf(v0[3]);
  o[4] = f2bf(v1[0]); o[5] = f2bf(v1[1]); o[6] = f2bf(v1[2]); o[7] = f2bf(v1[3]);
  *(bfrag*)(dst + i * 8) = o;
}

// ---------- convert + transpose: dst[n*K+k] = bf16(src[k*N+n]) ----------
__global__ __launch_bounds__(256) void cvt_T(const float* __restrict__ src,
                                             short* __restrict__ dst, int N, int K) {
  __shared__ short tile[64][65];
  int n0 = blockIdx.x * 64, k0 = blockIdx.y * 64;
  int tx = threadIdx.x & 63, ty = threadIdx.x >> 6;
  #pragma unroll
  for (int i = ty; i < 64; i += 4)
    tile[i][tx] = f2bf(src[(size_t)(k0 + i) * N + n0 + tx]);   // coalesced read
  __syncthreads();
  #pragma unroll
  for (int i = ty; i < 64; i += 4)
    dst[(size_t)(n0 + i) * K + k0 + tx] = tile[tx][i];         // coalesced write
}

// ---------- gate: g[row] = sigmoid(x[row,:] . Wg + bg) in fp32 ----------
__global__ __launch_bounds__(256) void gate_kernel(const float* __restrict__ x,
                                                   const float* __restrict__ Wg,
                                                   const float* __restrict__ bg,
                                                   float* __restrict__ g) {
  int row = blockIdx.x * 4 + (threadIdx.x >> 6);
  int l = threadIdx.x & 63;
  const facc* xr = (const facc*)(x + (size_t)row * 1024);
  const facc* wr = (const facc*)Wg;
  float s = 0.f;
  #pragma unroll
  for (int i = 0; i < 4; ++i) {
    facc a = xr[l + 64 * i], w = wr[l + 64 * i];
    s += a[0] * w[0] + a[1] * w[1] + a[2] * w[2] + a[3] * w[3];
  }
  #pragma unroll
  for (int mm = 1; mm < 64; mm <<= 1) s += __shfl_xor(s, mm);
  if (l == 0) g[row] = 1.f / (1.f + __expf(-(s + bg[0])));
}

// ---------- bf16 GEMM: C[M,N] = A[M,K] @ Bt[N,K]^T ----------
template <int EPI>
__global__ __launch_bounds__(256) void gemm_bt(
    const short* __restrict__ A, const short* __restrict__ Bt,
    int M, int N, int K,
    short* __restrict__ q_out, short* __restrict__ k_out, short* __restrict__ v_out,
    float* __restrict__ out, const float* __restrict__ bias) {
  __shared__ short Ab[128 * 32];
  __shared__ short Bb[128 * 32];
  const int t = threadIdx.x;
  const int l = t & 63;
  const int tile_m = blockIdx.y * 128;
  const int tile_n = blockIdx.x * 128;
  const int w = t >> 6;
  const int wm = (w >> 1) * 64, wn = (w & 1) * 64;
  const int c0 = t, c1 = t + 256;

  facc acc[4][4];
  #pragma unroll
  for (int i = 0; i < 4; ++i)
    #pragma unroll
    for (int j = 0; j < 4; ++j) acc[i][j] = (facc){0.f, 0.f, 0.f, 0.f};

  const short* Abase = A + (size_t)tile_m * K;
  const short* Bbase = Bt + (size_t)tile_n * K;

  for (int k0 = 0; k0 < K; k0 += 32) {
    bfrag a0 = *(const bfrag*)(Abase + (size_t)(c0 >> 2) * K + k0 + (c0 & 3) * 8);
    bfrag a1 = *(const bfrag*)(Abase + (size_t)(c1 >> 2) * K + k0 + (c1 & 3) * 8);
    bfrag b0 = *(const bfrag*)(Bbase + (size_t)(c0 >> 2) * K + k0 + (c0 & 3) * 8);
    bfrag b1 = *(const bfrag*)(Bbase + (size_t)(c1 >> 2) * K + k0 + (c1 & 3) * 8);
    __syncthreads();
    *(bfrag*)&Ab[c0 * 8] = a0;
    *(bfrag*)&Ab[c1 * 8] = a1;
    *(bfrag*)&Bb[c0 * 8] = b0;
    *(bfrag*)&Bb[c1 * 8] = b1;
    __syncthreads();
    bfrag af[4], bf[4];
    #pragma unroll
    for (int i = 0; i < 4; ++i)
      af[i] = *(const bfrag*)&Ab[(wm + i * 16 + (l & 15)) * 32 + ((l >> 4) << 3)];
    #pragma unroll
    for (int i = 0; i < 4; ++i)
      bf[i] = *(const bfrag*)&Bb[(wn + i * 16 + (l & 15)) * 32 + ((l >> 4) << 3)];
    #pragma unroll
    for (int mt = 0; mt < 4; ++mt)
      #pragma unroll
      for (int nt = 0; nt < 4; ++nt)
        acc[mt][nt] = __builtin_amdgcn_mfma_f32_16x16x32_bf16(af[mt], bf[nt], acc[mt][nt], 0, 0, 0);
  }

  #pragma unroll
  for (int mt = 0; mt < 4; ++mt)
    #pragma unroll
    for (int nt = 0; nt < 4; ++nt) {
      int col = tile_n + wn + nt * 16 + (l & 15);
      int row0 = tile_m + wm + mt * 16 + ((l >> 4) << 2);
      if (EPI == 0) {
        int which = col >> 10, rem = col & 1023, hh = rem >> 6, dd = rem & 63;
        short* dst = (which == 0) ? q_out : ((which == 1) ? k_out : v_out);
        #pragma unroll
        for (int r = 0; r < 4; ++r) {
          int m = row0 + r, b = m >> 12, s = m & 4095;
          dst[(((size_t)b * 16 + hh) * 4096 + s) * 64 + dd] = f2bf(acc[mt][nt][r]);
        }
      } else {
        float bv = bias[col];
        #pragma unroll
        for (int r = 0; r < 4; ++r)
          out[(size_t)(row0 + r) * N + col] = acc[mt][nt][r] + bv;
      }
    }
}

// ---------- fused attention: local window + strided global + gate combine ----------
// Block = 256 thr = 4 waves, each wave owns 32 q (2 sub-tiles of 16). 128 q/block.
// Swapped QK^T (mfma(K,Q) -> S^T, col=q): softmax row-reduce = 15 in-reg max + 2 shfl.
// K staged via pre-swizzled global source + linear b128 stores (write-conflict-free);
// V transpose-scattered with slot ^= (d&7)^(d>>3) (free both sides); all frag reads
// XOR-swizzled. Two online-softmax states (local / global), combined in epilogue.
#define SL 0.18033688011112043f   // 0.125 * log2(e)

__global__ __launch_bounds__(256) void attn_fused(
    const short* __restrict__ qg, const short* __restrict__ kg, const short* __restrict__ vg,
    const float* __restrict__ gate, short* __restrict__ comb) {
  __shared__ short Kt[64 * 64];       // [key][d], rows 128B, slot-swizzled
  __shared__ short Vt[64 * 64];       // [d][key], rows 128B, slot-swizzled
  __shared__ short Pb[4][2][16 * 64]; // per-wave, per-mt P [q][key]

  const int t = threadIdx.x, l = t & 63, w = t >> 6;
  const int bid = blockIdx.x;
  const int bh = bid >> 5, qblk = bid & 31;
  const int q0 = qblk * 128;
  const int b = bh >> 4, h = bh & 15;
  const int lo = l & 15, hi = l >> 4, hi4 = (l >> 4) << 2;

  const int n = q0 >> 9;
  int kstart = n * 512 - 256; if (kstart < 0) kstart = 0;
  int kend = n * 512 + 768; if (kend > 4096) kend = 4096;
  const int nloc = (kend - kstart) >> 6;
  const int nIter = nloc + 2;          // + 2 tiles of 64 strided-global keys (128 total)

  // Q fragments (B-operand layout: lane holds q-row lo, d-chunk hi*8, two 32-halves)
  const size_t qrow = (size_t)bh * 4096 + q0 + w * 32;
  bfrag qf[2][2];
  #pragma unroll
  for (int mt = 0; mt < 2; ++mt)
    #pragma unroll
    for (int hf = 0; hf < 2; ++hf)
      qf[mt][hf] = *(const bfrag*)(qg + (qrow + mt * 16 + lo) * 64 + hf * 32 + hi * 8);

  float m_l[2] = {-3e38f, -3e38f}, s_l[2] = {0.f, 0.f};
  float m_g[2] = {-3e38f, -3e38f}, s_g[2] = {0.f, 0.f};
  facc o_l[2][4], o_g[2][4];
  #pragma unroll
  for (int mt = 0; mt < 2; ++mt)
    #pragma unroll
    for (int nt = 0; nt < 4; ++nt) {
      o_l[mt][nt] = (facc){0.f, 0.f, 0.f, 0.f};
      o_g[mt][nt] = (facc){0.f, 0.f, 0.f, 0.f};
    }

  const int c0 = t, c1 = t + 256;      // 16B chunk ids: key = c>>3, slot = c&7
  const int kk0 = c0 >> 3, kk1 = c1 >> 3;
  const int slK0 = (c0 & 7) ^ ((kk0 & 7) ^ (kk0 >> 3));   // pre-swizzled K source slot
  const int slK1 = (c1 & 7) ^ ((kk1 & 7) ^ (kk1 >> 3));

  auto krowOf = [&](int it2, int kk) -> int {
    return (it2 < nloc) ? (kstart + it2 * 64 + kk) : (((it2 - nloc) * 64 + kk) * 32);
  };

  // prologue: prefetch tile 0 into regs
  bfrag ka, kb2, va, vb2;
  {
    ka  = *(const bfrag*)(kg + ((size_t)bh * 4096 + krowOf(0, kk0)) * 64 + slK0 * 8);
    kb2 = *(const bfrag*)(kg + ((size_t)bh * 4096 + krowOf(0, kk1)) * 64 + slK1 * 8);
    va  = *(const bfrag*)(vg + ((size_t)bh * 4096 + krowOf(0, kk0)) * 64 + (c0 & 7) * 8);
    vb2 = *(const bfrag*)(vg + ((size_t)bh * 4096 + krowOf(0, kk1)) * 64 + (c1 & 7) * 8);
  }

  for (int it = 0; it < nIter; ++it) {
    const bool isLoc = it < nloc;
    __syncthreads();                                   // prev tile fully consumed
    // K: linear store (conflict-free); source was pre-swizzled
    *(bfrag*)&Kt[c0 * 8] = ka;
    *(bfrag*)&Kt[c1 * 8] = kb2;
    // V: transpose scatter, swizzled slot varies per lane -> ~2-way max
    {
      int dbase = (c0 & 7) * 8;
      #pragma unroll
      for (int jj = 0; jj < 8; ++jj) {
        int d = dbase + jj; int gd = (d & 7) ^ (d >> 3);
        Vt[d * 64 + (kk0 ^ (gd << 3))] = va[jj];
      }
      dbase = (c1 & 7) * 8;
      #pragma unroll
      for (int jj = 0; jj < 8; ++jj) {
        int d = dbase + jj; int gd = (d & 7) ^ (d >> 3);
        Vt[d * 64 + (kk1 ^ (gd << 3))] = vb2[jj];
      }
    }
    // prefetch next tile (overlaps barrier + compute)
    if (it + 1 < nIter) {
      ka  = *(const bfrag*)(kg + ((size_t)bh * 4096 + krowOf(it + 1, kk0)) * 64 + slK0 * 8);
      kb2 = *(const bfrag*)(kg + ((size_t)bh * 4096 + krowOf(it + 1, kk1)) * 64 + slK1 * 8);
      va  = *(const bfrag*)(vg + ((size_t)bh * 4096 + krowOf(it + 1, kk0)) * 64 + (c0 & 7) * 8);
      vb2 = *(const bfrag*)(vg + ((size_t)bh * 4096 + krowOf(it + 1, kk1)) * 64 + (c1 & 7) * 8);
    }
    __syncthreads();                                   // tile visible

    // K frags (A-operand: row = key)
    bfrag kf[4][2];
    #pragma unroll
    for (int kt = 0; kt < 4; ++kt) {
      int key = kt * 16 + lo; int gk2 = (key & 7) ^ (key >> 3);
      const short* Kr = &Kt[key * 64];
      kf[kt][0] = *(const bfrag*)&Kr[(hi * 8) ^ (gk2 << 3)];
      kf[kt][1] = *(const bfrag*)&Kr[(32 + hi * 8) ^ (gk2 << 3)];
    }
    // S^T = K @ Q^T : col = q (lane lo), rows = keys hi4..hi4+3 (+16*kt)
    facc sA[2][4];
    #pragma unroll
    for (int mt = 0; mt < 2; ++mt)
      #pragma unroll
      for (int kt = 0; kt < 4; ++kt) {
        facc z = (facc){0.f, 0.f, 0.f, 0.f};
        z = __builtin_amdgcn_mfma_f32_16x16x32_bf16(kf[kt][0], qf[mt][0], z, 0, 0, 0);
        z = __builtin_amdgcn_mfma_f32_16x16x32_bf16(kf[kt][1], qf[mt][1], z, 0, 0, 0);
        sA[mt][kt] = z;
      }
    // V frags (B-operand from Vt[d][key])
    bfrag vf[4][2];
    #pragma unroll
    for (int nt = 0; nt < 4; ++nt) {
      int d = nt * 16 + lo; int gd = (d & 7) ^ (d >> 3);
      const short* Vr = &Vt[d * 64];
      vf[nt][0] = *(const bfrag*)&Vr[(hi * 8) ^ (gd << 3)];
      vf[nt][1] = *(const bfrag*)&Vr[(32 + hi * 8) ^ (gd << 3)];
    }

    short* PwBase = &Pb[w][0][0];
    auto processTile = [&](float (&mst)[2], float (&lsum)[2], facc (&oacc)[2][4]) {
      #pragma unroll
      for (int mt = 0; mt < 2; ++mt) {
        float tm = -3e38f;
        #pragma unroll
        for (int kt = 0; kt < 4; ++kt)
          #pragma unroll
          for (int r = 0; r < 4; ++r) tm = fmaxf(tm, sA[mt][kt][r]);
        tm = fmaxf(tm, __shfl_xor(tm, 16));
        tm = fmaxf(tm, __shfl_xor(tm, 32));      // lanes {l,l^16,l^32,l^48} share q=lo
        float mnew = fmaxf(mst[mt], tm);
        float corr = exp2f((mst[mt] - mnew) * SL);
        mst[mt] = mnew;
        float ps = 0.f;
        short4v pk[4];
        #pragma unroll
        for (int kt = 0; kt < 4; ++kt)
          #pragma unroll
          for (int r = 0; r < 4; ++r) {
            float p = exp2f((sA[mt][kt][r] - mnew) * SL);
            ps += p;
            pk[kt][r] = f2bf(p);
          }
        lsum[mt] = lsum[mt] * corr + ps;
        short* Pw = PwBase + mt * 1024;
        const int gq = (lo & 7) ^ (lo >> 3);
        #pragma unroll
        for (int kt = 0; kt < 4; ++kt)
          *(short4v*)&Pw[lo * 64 + ((kt * 16 + hi4) ^ (gq << 3))] = pk[kt];
        float cr[4];
        #pragma unroll
        for (int r = 0; r < 4; ++r) cr[r] = __shfl(corr, hi4 + r);
        bfrag pf0 = *(const bfrag*)&Pw[lo * 64 + ((hi * 8) ^ (gq << 3))];
        bfrag pf1 = *(const bfrag*)&Pw[lo * 64 + ((32 + hi * 8) ^ (gq << 3))];
        #pragma unroll
        for (int nt = 0; nt < 4; ++nt) {
          facc oo = oacc[mt][nt];
          #pragma unroll
          for (int r = 0; r < 4; ++r) oo[r] *= cr[r];
          oo = __builtin_amdgcn_mfma_f32_16x16x32_bf16(pf0, vf[nt][0], oo, 0, 0, 0);
          oo = __builtin_amdgcn_mfma_f32_16x16x32_bf16(pf1, vf[nt][1], oo, 0, 0, 0);
          oacc[mt][nt] = oo;
        }
      }
    };
    if (isLoc) processTile(m_l, s_l, o_l);
    else       processTile(m_g, s_g, o_g);
  }

  // epilogue: finish both softmaxes, gate-combine, write comb [b*s][h*64+d]
  #pragma unroll
  for (int mt = 0; mt < 2; ++mt) {
    float Ll = s_l[mt]; Ll += __shfl_xor(Ll, 16); Ll += __shfl_xor(Ll, 32);
    float Lg = s_g[mt]; Lg += __shfl_xor(Lg, 16); Lg += __shfl_xor(Lg, 32);
    #pragma unroll
    for (int r = 0; r < 4; ++r) {
      int qr = hi4 + r;
      float invl = 1.f / __shfl(Ll, qr);
      float invg = 1.f / __shfl(Lg, qr);
      int q = q0 + w * 32 + mt * 16 + qr;
      float gg = gate[b * 4096 + q];
      size_t obase = ((size_t)b * 4096 + q) * 1024 + h * 64;
      #pragma unroll
      for (int nt = 0; nt < 4; ++nt) {
        float val = gg * o_l[mt][nt][r] * invl + (1.f - gg) * o_g[mt][nt][r] * invg;
        comb[obase + nt * 16 + lo] = f2bf(val);
      }
    }
  }
}

// ---------- launch ----------
extern "C" void kernel_launch(void* const* d_in, const int* in_sizes, int n_in,
                              void* d_out, int out_size, void* d_ws, size_t ws_size,
                              hipStream_t stream) {
  const float* x    = (const float*)d_in[0];
  const float* Wqkv = (const float*)d_in[1];
  const float* Wg   = (const float*)d_in[2];
  const float* bg   = (const float*)d_in[3];
  const float* Wout = (const float*)d_in[4];
  const float* bout = (const float*)d_in[5];
  float* out = (float*)d_out;

  char* p = (char*)d_ws;
  short* xbf   = (short*)p; p += (size_t)8192 * 1024 * 2;   // reused as comb
  short* WqkvT = (short*)p; p += (size_t)3072 * 1024 * 2;
  short* WoutT = (short*)p; p += (size_t)1024 * 1024 * 2;
  short* qb    = (short*)p; p += (size_t)32 * 4096 * 64 * 2;
  short* kb    = (short*)p; p += (size_t)32 * 4096 * 64 * 2;
  short* vb    = (short*)p; p += (size_t)32 * 4096 * 64 * 2;
  float* g     = (float*)p; p += (size_t)8192 * 4;
  short* comb  = xbf;  // alias: xbf dead after gemm<0>

  cvt_rows<<<4096, 256, 0, stream>>>(x, xbf, (size_t)8192 * 1024 / 8);
  cvt_T<<<dim3(48, 16), 256, 0, stream>>>(Wqkv, WqkvT, 3072, 1024);
  cvt_T<<<dim3(16, 16), 256, 0, stream>>>(Wout, WoutT, 1024, 1024);
  gate_kernel<<<2048, 256, 0, stream>>>(x, Wg, bg, g);
  gemm_bt<0><<<dim3(24, 64), 256, 0, stream>>>(xbf, WqkvT, 8192, 3072, 1024,
                                               qb, kb, vb, nullptr, nullptr);
  attn_fused<<<1024, 256, 0, stream>>>(qb, kb, vb, g, comb);
  gemm_bt<1><<<dim3(8, 64), 256, 0, stream>>>(comb, WoutT, 8192, 1024, 1024,
                                              nullptr, nullptr, nullptr, out, bout);
}